// Round 1
// baseline (8083.914 us; speedup 1.0000x reference)
//
#include <hip/hip_runtime.h>

#define NBLK 1024   // molecules
#define NP   22     // atoms per molecule
#define NH   64     // hidden
#define NL   5      // layers
#define NE   21     // edges per row (directed, to every other atom)

constexpr float CRc    = 3.0f;  // 15/L
constexpr float LOG2Mc = 7.0f;

__device__ __forceinline__ float wsum(float v) {
#pragma unroll
  for (int m = 32; m >= 1; m >>= 1) v += __shfl_xor(v, m, 64);
  return v;
}

__device__ __forceinline__ void ldsfence() {
  asm volatile("s_waitcnt lgkmcnt(0)" ::: "memory");
}

__device__ __forceinline__ float siluf(float s) {
  return s / (1.0f + __expf(-s));
}

__global__ __launch_bounds__(256) void egnn_kernel(
    const float* __restrict__ t,   const float* __restrict__ x,
    const float* __restrict__ embW, const float* __restrict__ embB,
    const float* __restrict__ ew1, const float* __restrict__ eb1,
    const float* __restrict__ ew2, const float* __restrict__ eb2,
    const float* __restrict__ nw1, const float* __restrict__ nb1,
    const float* __restrict__ nw2, const float* __restrict__ nb2,
    const float* __restrict__ cw1, const float* __restrict__ cb1,
    const float* __restrict__ cw2, const float* __restrict__ aw,
    const float* __restrict__ ab,  float* __restrict__ out)
{
  __shared__ __align__(16) float h_buf[2][NP][NH];   // node features, double-buffered
  __shared__ __align__(16) float cbuf[2][NP][4];     // coords, double-buffered (padded)
  __shared__ __align__(16) float c0s[NP][4];         // initial coords
  __shared__ __align__(16) float eas[NP][NE];        // initial squared distances
  __shared__ __align__(16) float mbuf[4][NE][NH];    // per-wave edge activations
  __shared__ float vels[NP][4];
  __shared__ float velm[4];

  const int b    = blockIdx.x;
  const int tid  = threadIdx.x;
  const int lane = tid & 63;
  const int wv   = tid >> 6;

  // ---- initial coords
  if (tid < NP * 3) {
    int p = tid / 3, c = tid - p * 3;
    float v = x[b * (NP * 3) + tid];
    c0s[p][c]     = v;
    cbuf[0][p][c] = v;
  }
  // ---- initial h:  one-hot @ emb_W  ->  emb_W[p] + t*emb_W[22] + 7*emb_W[23] + emb_b
  float tb = t[b];
  for (int p = wv; p < NP; p += 4) {
    h_buf[0][p][lane] = embW[p * NH + lane] + tb * embW[22 * NH + lane]
                      + LOG2Mc * embW[23 * NH + lane] + embB[lane];
  }
  __syncthreads();
  // ---- edge_attr = initial squared distances
  for (int idx = tid; idx < NP * NE; idx += 256) {
    int r = idx / NE, e = idx - r * NE;
    int col = e + (e >= r);
    float dx = c0s[r][0] - c0s[col][0];
    float dy = c0s[r][1] - c0s[col][1];
    float dz = c0s[r][2] - c0s[col][2];
    eas[r][e] = dx * dx + dy * dy + dz * dz;
  }
  __syncthreads();

  for (int l = 0; l < NL; ++l) {
    const int cur = l & 1, nxt = cur ^ 1;
    const float* W1  = ew1 + l * 130 * NH;
    const float* B1  = eb1 + l * NH;
    const float* W2  = ew2 + l * NH * NH;
    const float* B2  = eb2 + l * NH;
    const float* N1  = nw1 + l * 128 * NH;
    const float* Nb1 = nb1 + l * NH;
    const float* N2  = nw2 + l * NH * NH;
    const float* Nb2 = nb2 + l * NH;
    const float* C1  = cw1 + l * NH * NH;
    const float* Cb1 = cb1 + l * NH;
    const float* C2  = cw2 + l * NH;
    const float* AWl = aw  + l * NH;
    const float  abl = ab[l];

    for (int r = wv; r < NP; r += 4) {
      // ---- hi_part: h[r] @ W1[0:64]  (shared by all 21 edges of this row)
      const float4* hr4 = reinterpret_cast<const float4*>(&h_buf[cur][r][0]);
      float a0 = 0.f, a1 = 0.f, a2 = 0.f, a3 = 0.f;
#pragma unroll
      for (int kk = 0; kk < 16; ++kk) {
        float4 hv = hr4[kk];
        a0 = fmaf(hv.x, W1[(4 * kk + 0) * NH + lane], a0);
        a1 = fmaf(hv.y, W1[(4 * kk + 1) * NH + lane], a1);
        a2 = fmaf(hv.z, W1[(4 * kk + 2) * NH + lane], a2);
        a3 = fmaf(hv.w, W1[(4 * kk + 3) * NH + lane], a3);
      }
      float hi_part = (a0 + a1) + (a2 + a3) + B1[lane];

      float wreg[64];
#pragma unroll
      for (int k = 0; k < 64; ++k) wreg[k] = W1[(64 + k) * NH + lane];
      float w128 = W1[128 * NH + lane], w129 = W1[129 * NH + lane];
      float cix = cbuf[cur][r][0], ciy = cbuf[cur][r][1], ciz = cbuf[cur][r][2];

      // ---- phase A: edge MLP layer 1
      for (int e = 0; e < NE; ++e) {
        int col = e + (e >= r);
        float ccx = cbuf[cur][col][0], ccy = cbuf[cur][col][1], ccz = cbuf[cur][col][2];
        float dx = cix - ccx, dy = ciy - ccy, dz = ciz - ccz;
        float radial = dx * dx + dy * dy + dz * dz;
        float acc0 = fmaf(radial, w128, hi_part);
        float acc1 = eas[r][e] * w129, acc2 = 0.f, acc3 = 0.f;
        const float4* hc4 = reinterpret_cast<const float4*>(&h_buf[cur][col][0]);
#pragma unroll
        for (int kk = 0; kk < 16; ++kk) {
          float4 hv = hc4[kk];
          acc0 = fmaf(hv.x, wreg[4 * kk + 0], acc0);
          acc1 = fmaf(hv.y, wreg[4 * kk + 1], acc1);
          acc2 = fmaf(hv.z, wreg[4 * kk + 2], acc2);
          acc3 = fmaf(hv.w, wreg[4 * kk + 3], acc3);
        }
        float s = (acc0 + acc1) + (acc2 + acc3);
        mbuf[wv][e][lane] = siluf(s);
      }
      ldsfence();

      // ---- phase B: edge MLP layer 2 + attention gate; accumulate agg
#pragma unroll
      for (int k = 0; k < 64; ++k) wreg[k] = W2[k * NH + lane];
      float b2 = B2[lane], awl = AWl[lane];
      float aggl = 0.f;
      for (int e = 0; e < NE; ++e) {
        const float4* mp = reinterpret_cast<const float4*>(&mbuf[wv][e][0]);
        float acc0 = b2, acc1 = 0.f, acc2 = 0.f, acc3 = 0.f;
#pragma unroll
        for (int kk = 0; kk < 16; ++kk) {
          float4 mv = mp[kk];
          acc0 = fmaf(mv.x, wreg[4 * kk + 0], acc0);
          acc1 = fmaf(mv.y, wreg[4 * kk + 1], acc1);
          acc2 = fmaf(mv.z, wreg[4 * kk + 2], acc2);
          acc3 = fmaf(mv.w, wreg[4 * kk + 3], acc3);
        }
        float s  = (acc0 + acc1) + (acc2 + acc3);
        float m2 = siluf(s);
        float g  = wsum(m2 * awl) + abl;
        float mg = m2 * (1.0f / (1.0f + __expf(-g)));
        aggl += mg;
        mbuf[wv][e][lane] = mg;
      }
      ldsfence();

      // ---- phase C: coordinate MLP + coord accumulation
#pragma unroll
      for (int k = 0; k < 64; ++k) wreg[k] = C1[k * NH + lane];
      float cb = Cb1[lane], c2l = C2[lane];
      float cax = 0.f, cay = 0.f, caz = 0.f;
      for (int e = 0; e < NE; ++e) {
        const float4* mp = reinterpret_cast<const float4*>(&mbuf[wv][e][0]);
        float acc0 = cb, acc1 = 0.f, acc2 = 0.f, acc3 = 0.f;
#pragma unroll
        for (int kk = 0; kk < 16; ++kk) {
          float4 mv = mp[kk];
          acc0 = fmaf(mv.x, wreg[4 * kk + 0], acc0);
          acc1 = fmaf(mv.y, wreg[4 * kk + 1], acc1);
          acc2 = fmaf(mv.z, wreg[4 * kk + 2], acc2);
          acc3 = fmaf(mv.w, wreg[4 * kk + 3], acc3);
        }
        float s   = (acc0 + acc1) + (acc2 + acc3);
        float c1v = siluf(s);
        float dot = wsum(c1v * c2l);                       // m @ cw2 (no bias)
        float tv  = (1.0f - 2.0f / (1.0f + __expf(2.0f * dot))) * CRc;
        int col = e + (e >= r);
        float ccx = cbuf[cur][col][0], ccy = cbuf[cur][col][1], ccz = cbuf[cur][col][2];
        float dx = cix - ccx, dy = ciy - ccy, dz = ciz - ccz;
        float radial = dx * dx + dy * dy + dz * dz;
        float f = tv / (sqrtf(radial) + 1.0f);
        cax = fmaf(dx, f, cax);
        cay = fmaf(dy, f, cay);
        caz = fmaf(dz, f, caz);
      }

      // ---- node update for row r
      float na0 = Nb1[lane], na1 = 0.f, na2 = 0.f, na3 = 0.f;
#pragma unroll
      for (int kk = 0; kk < 16; ++kk) {
        float4 hv = hr4[kk];
        na0 = fmaf(hv.x, N1[(4 * kk + 0) * NH + lane], na0);
        na1 = fmaf(hv.y, N1[(4 * kk + 1) * NH + lane], na1);
        na2 = fmaf(hv.z, N1[(4 * kk + 2) * NH + lane], na2);
        na3 = fmaf(hv.w, N1[(4 * kk + 3) * NH + lane], na3);
      }
      mbuf[wv][0][lane] = aggl;   // broadcast agg across lanes
      ldsfence();
      const float4* ag4 = reinterpret_cast<const float4*>(&mbuf[wv][0][0]);
#pragma unroll
      for (int kk = 0; kk < 16; ++kk) {
        float4 av = ag4[kk];
        na0 = fmaf(av.x, N1[(64 + 4 * kk + 0) * NH + lane], na0);
        na1 = fmaf(av.y, N1[(64 + 4 * kk + 1) * NH + lane], na1);
        na2 = fmaf(av.z, N1[(64 + 4 * kk + 2) * NH + lane], na2);
        na3 = fmaf(av.w, N1[(64 + 4 * kk + 3) * NH + lane], na3);
      }
      float sn  = (na0 + na1) + (na2 + na3);
      float nh1 = siluf(sn);
      mbuf[wv][1][lane] = nh1;
      ldsfence();
      const float4* nh4 = reinterpret_cast<const float4*>(&mbuf[wv][1][0]);
      float q0 = Nb2[lane], q1 = 0.f, q2 = 0.f, q3 = 0.f;
#pragma unroll
      for (int kk = 0; kk < 16; ++kk) {
        float4 nv = nh4[kk];
        q0 = fmaf(nv.x, N2[(4 * kk + 0) * NH + lane], q0);
        q1 = fmaf(nv.y, N2[(4 * kk + 1) * NH + lane], q1);
        q2 = fmaf(nv.z, N2[(4 * kk + 2) * NH + lane], q2);
        q3 = fmaf(nv.w, N2[(4 * kk + 3) * NH + lane], q3);
      }
      h_buf[nxt][r][lane] = h_buf[cur][r][lane] + ((q0 + q1) + (q2 + q3));
      if (lane < 3) {
        float ca = (lane == 0) ? cax : ((lane == 1) ? cay : caz);
        cbuf[nxt][r][lane] = cbuf[cur][r][lane] + ca;
      }
    }
    __syncthreads();
  }

  // ---- output: vel = coord - coord0, mean over atoms removed. Final coords in cbuf[1].
  if (tid < NP * 3) {
    int p = tid / 3, c = tid - p * 3;
    vels[p][c] = cbuf[1][p][c] - c0s[p][c];
  }
  __syncthreads();
  if (tid < 3) {
    float s = 0.f;
    for (int p = 0; p < NP; ++p) s += vels[p][tid];
    velm[tid] = s / 22.0f;
  }
  __syncthreads();
  if (tid < NP * 3) {
    int p = tid / 3, c = tid - p * 3;
    out[b * (NP * 3) + tid] = vels[p][c] - velm[c];
  }
}

extern "C" void kernel_launch(void* const* d_in, const int* in_sizes, int n_in,
                              void* d_out, int out_size, void* d_ws, size_t ws_size,
                              hipStream_t stream) {
  const float* t    = (const float*)d_in[0];
  const float* x    = (const float*)d_in[1];
  const float* embW = (const float*)d_in[2];
  const float* embB = (const float*)d_in[3];
  // d_in[4] out_W, d_in[5] out_b: do not affect the returned velocities
  const float* ew1  = (const float*)d_in[6];
  const float* eb1  = (const float*)d_in[7];
  const float* ew2  = (const float*)d_in[8];
  const float* eb2  = (const float*)d_in[9];
  const float* nw1  = (const float*)d_in[10];
  const float* nb1  = (const float*)d_in[11];
  const float* nw2  = (const float*)d_in[12];
  const float* nb2  = (const float*)d_in[13];
  const float* cw1  = (const float*)d_in[14];
  const float* cb1  = (const float*)d_in[15];
  const float* cw2  = (const float*)d_in[16];
  const float* aw   = (const float*)d_in[17];
  const float* ab   = (const float*)d_in[18];
  // d_in[19] rows, d_in[20] cols: edge list is regenerated analytically in-kernel

  egnn_kernel<<<NBLK, 256, 0, stream>>>(t, x, embW, embB, ew1, eb1, ew2, eb2,
                                        nw1, nb1, nw2, nb2, cw1, cb1, cw2,
                                        aw, ab, (float*)d_out);
}

// Round 3
// 2313.776 us; speedup vs baseline: 3.4938x; 3.4938x over previous
//
#include <hip/hip_runtime.h>

#define NP 22
#define NH 64
#define NL 5
#define NE 21
#define HS 66   // h_lds row stride in floats (padded: bank-spread for transposed reads)

constexpr float CRc    = 3.0f;   // 15/L
constexpr float LOG2Mc = 7.0f;

typedef __fp16 h2_t __attribute__((ext_vector_type(2)));

__device__ __forceinline__ float rl_f(float v, int lane) {
  return __builtin_bit_cast(float, __builtin_amdgcn_readlane(__builtin_bit_cast(int, v), lane));
}
__device__ __forceinline__ h2_t rl_h2(h2_t v, int lane) {
  return __builtin_bit_cast(h2_t, __builtin_amdgcn_readlane(__builtin_bit_cast(int, v), lane));
}
__device__ __forceinline__ h2_t pkf(float a, float b) {
  return __builtin_amdgcn_cvt_pkrtz(a, b);
}
// lane 2c ends up holding (v_{2c}, v_{2c+1}) — readlane from even lanes only.
__device__ __forceinline__ h2_t pkpair(float v) {
  float o = __shfl_xor(v, 1, 64);
  return pkf(v, o);
}

__device__ __forceinline__ float fdot2(h2_t a, h2_t b, float c) {
#if __has_builtin(__builtin_amdgcn_fdot2)
  return __builtin_amdgcn_fdot2(a, b, c, false);
#else
  float d;
  asm("v_dot2_f32_f16 %0, %1, %2, %3"
      : "=v"(d)
      : "v"(__builtin_bit_cast(int, a)), "v"(__builtin_bit_cast(int, b)), "v"(c));
  return d;
#endif
}

__device__ __forceinline__ float wsum(float v) {
#pragma unroll
  for (int m = 32; m >= 1; m >>= 1) v += __shfl_xor(v, m, 64);
  return v;
}

__device__ __forceinline__ float siluf(float s) { return s / (1.0f + __expf(-s)); }

// y_j = INIT + sum_k h[LANEIDX][k] * Wpk[k][j]   (64-K GEMV via 32 readlane + 32 dot2)
#define GEMV_HT(OUT, LANEIDX, W, INIT) do {                                 \
  float _a0 = (INIT), _a1 = 0.f, _a2 = 0.f, _a3 = 0.f;                      \
  _Pragma("unroll")                                                         \
  for (int _c = 0; _c < 32; _c += 4) {                                      \
    _a0 = fdot2(rl_h2(hT[_c + 0], (LANEIDX)), W[_c + 0], _a0);              \
    _a1 = fdot2(rl_h2(hT[_c + 1], (LANEIDX)), W[_c + 1], _a1);              \
    _a2 = fdot2(rl_h2(hT[_c + 2], (LANEIDX)), W[_c + 2], _a2);              \
    _a3 = fdot2(rl_h2(hT[_c + 3], (LANEIDX)), W[_c + 3], _a3);              \
  }                                                                         \
  OUT = (_a0 + _a1) + (_a2 + _a3);                                          \
} while (0)

// y_j = INIT + sum_k src[k] * Wpk[k][j], src pair-packed per-lane (read even lanes)
#define GEMV_PK(OUT, SRC, W, INIT) do {                                     \
  float _a0 = (INIT), _a1 = 0.f, _a2 = 0.f, _a3 = 0.f;                      \
  _Pragma("unroll")                                                         \
  for (int _c = 0; _c < 32; _c += 4) {                                      \
    _a0 = fdot2(rl_h2((SRC), 2 * (_c + 0)), W[_c + 0], _a0);                \
    _a1 = fdot2(rl_h2((SRC), 2 * (_c + 1)), W[_c + 1], _a1);                \
    _a2 = fdot2(rl_h2((SRC), 2 * (_c + 2)), W[_c + 2], _a2);                \
    _a3 = fdot2(rl_h2((SRC), 2 * (_c + 3)), W[_c + 3], _a3);                \
  }                                                                         \
  OUT = (_a0 + _a1) + (_a2 + _a3);                                          \
} while (0)

#define LOADW(DST, SRC) do {                                                \
  _Pragma("unroll")                                                         \
  for (int _c = 0; _c < 32; ++_c)                                           \
    DST[_c] = pkf((SRC)[(2 * _c) * NH + lane],                              \
                  (SRC)[(2 * _c + 1) * NH + lane]);                         \
} while (0)

__global__ __launch_bounds__(256, 2) void egnn_kernel(
    const float* __restrict__ t,   const float* __restrict__ x,
    const float* __restrict__ embW, const float* __restrict__ embB,
    const float* __restrict__ ew1, const float* __restrict__ eb1,
    const float* __restrict__ ew2, const float* __restrict__ eb2,
    const float* __restrict__ nw1, const float* __restrict__ nb1,
    const float* __restrict__ nw2, const float* __restrict__ nb2,
    const float* __restrict__ cw1, const float* __restrict__ cb1,
    const float* __restrict__ cw2, const float* __restrict__ aw,
    const float* __restrict__ ab,  float* __restrict__ out)
{
  __shared__ float h_lds[NP * HS];      // fp32 master copy of h
  __shared__ float hibuf[NP * NH];      // per-row hi_part (per-lane=ch)
  __shared__ float aggbuf[NP * NH];     // per-row agg (per-lane=ch)
  __shared__ float eas[NP * NE];        // initial squared distances
  __shared__ float cbuf[NP][4];         // fp32 master coords
  __shared__ float c0s[NP][4];
  __shared__ float cupd[NP][4];
  __shared__ float vels[NP][4];
  __shared__ float velm[4];

  const int b = blockIdx.x, tid = threadIdx.x;
  const int lane = tid & 63, wv = tid >> 6;
  const int pl = (lane < NP) ? lane : 0;   // clamped atom index for transposed regs

  // ---- init coords + h master
  if (tid < NP * 3) {
    int p = tid / 3, c = tid - p * 3;
    float v = x[b * (NP * 3) + tid];
    c0s[p][c] = v; cbuf[p][c] = v;
  }
  float tb = t[b];
  for (int p = wv; p < NP; p += 4)
    h_lds[p * HS + lane] = embW[p * NH + lane] + tb * embW[22 * NH + lane]
                         + LOG2Mc * embW[23 * NH + lane] + embB[lane];
  __syncthreads();

  // ---- edge_attr table
  for (int idx = tid; idx < NP * NE; idx += 256) {
    int r = idx / NE, e = idx - r * NE, col = e + (e >= r);
    float dx = c0s[r][0] - c0s[col][0];
    float dy = c0s[r][1] - c0s[col][1];
    float dz = c0s[r][2] - c0s[col][2];
    eas[idx] = dx * dx + dy * dy + dz * dz;
  }

  // ---- transposed register caches (lane = atom)
  h2_t hT[32];
#pragma unroll
  for (int c = 0; c < 32; ++c)
    hT[c] = pkf(h_lds[pl * HS + 2 * c], h_lds[pl * HS + 2 * c + 1]);
  float cTx = cbuf[pl][0], cTy = cbuf[pl][1], cTz = cbuf[pl][2];
  __syncthreads();

  h2_t wA[32], wB[32], wC[32];

  for (int l = 0; l < NL; ++l) {
    const float* W1 = ew1 + l * 130 * NH;
    const float* W2 = ew2 + l * NH * NH;
    const float* C1 = cw1 + l * NH * NH;
    const float* N1 = nw1 + l * 128 * NH;
    const float* N2 = nw2 + l * NH * NH;

    // ---- hi_part for own rows: h[r] @ W1[0:64] + B1
    LOADW(wA, W1);
    {
      float b1l = eb1[l * NH + lane];
      for (int r = wv; r < NP; r += 4) {
        float s; GEMV_HT(s, r, wA, b1l);
        hibuf[r * NH + lane] = s;
      }
    }

    // ---- edge-phase weights
    LOADW(wA, W1 + 64 * NH);   // W1 rows 64..127 (h[col] part)
    LOADW(wB, W2);
    LOADW(wC, C1);
    float w128 = W1[128 * NH + lane], w129 = W1[129 * NH + lane];
    float b2l  = eb2[l * NH + lane],  awl = aw[l * NH + lane], abl = ab[l];
    float cb1l = cb1[l * NH + lane],  c2l = cw2[l * NH + lane];

    // ---- edge phase (fused MLP1 -> MLP2+gate -> coord MLP per edge)
    for (int r = wv; r < NP; r += 4) {
      float hii = hibuf[r * NH + lane];
      float cix = rl_f(cTx, r), ciy = rl_f(cTy, r), ciz = rl_f(cTz, r);
      float aggl = 0.f, cax = 0.f, cay = 0.f, caz = 0.f;
      for (int e = 0; e < NE; ++e) {
        int col = e + (e >= r);
        float ccx = rl_f(cTx, col), ccy = rl_f(cTy, col), ccz = rl_f(cTz, col);
        float dx = cix - ccx, dy = ciy - ccy, dz = ciz - ccz;
        float radial = dx * dx + dy * dy + dz * dz;

        float init = fmaf(radial, w128, fmaf(eas[r * NE + e], w129, hii));
        float s1; GEMV_HT(s1, col, wA, init);
        float m1 = siluf(s1);
        h2_t m1p = pkpair(m1);

        float s2; GEMV_PK(s2, m1p, wB, b2l);
        float m2 = siluf(s2);
        float g  = wsum(m2 * awl) + abl;
        float mg = m2 * (1.0f / (1.0f + __expf(-g)));
        aggl += mg;
        h2_t mgp = pkpair(mg);

        float s3; GEMV_PK(s3, mgp, wC, cb1l);
        float c1v = siluf(s3);
        float dot = wsum(c1v * c2l);
        float tv  = (1.0f - 2.0f / (1.0f + __expf(2.0f * dot))) * CRc;
        float f   = tv / (sqrtf(radial) + 1.0f);
        cax = fmaf(dx, f, cax); cay = fmaf(dy, f, cay); caz = fmaf(dz, f, caz);
      }
      aggbuf[r * NH + lane] = aggl;
      if (lane < 3) cupd[r][lane] = (lane == 0) ? cax : ((lane == 1) ? cay : caz);
    }

    // ---- node phase
    LOADW(wA, N1);             // h part
    LOADW(wB, N1 + 64 * NH);   // agg part
    LOADW(wC, N2);
    {
      float nb1l = nb1[l * NH + lane], nb2l = nb2[l * NH + lane];
      for (int r = wv; r < NP; r += 4) {
        float aggl = aggbuf[r * NH + lane];
        h2_t agp = pkpair(aggl);
        float s; GEMV_HT(s, r, wA, nb1l);
        float s2; GEMV_PK(s2, agp, wB, s);
        float nh1 = siluf(s2);
        h2_t np = pkpair(nh1);
        float q; GEMV_PK(q, np, wC, nb2l);
        h_lds[r * HS + lane] += q;     // fp32 residual update (own row only)
      }
    }

    __syncthreads();                   // h_lds & cupd complete
    if (tid < NP * 3) {
      int p = tid / 3, c = tid - p * 3;
      cbuf[p][c] += cupd[p][c];
    }
    __syncthreads();                   // cbuf updated
#pragma unroll
    for (int c = 0; c < 32; ++c)
      hT[c] = pkf(h_lds[pl * HS + 2 * c], h_lds[pl * HS + 2 * c + 1]);
    cTx = cbuf[pl][0]; cTy = cbuf[pl][1]; cTz = cbuf[pl][2];
    __syncthreads();                   // rebuild done before next layer's writes
  }

  // ---- output: vel = coord - coord0, mean-removed
  if (tid < NP * 3) {
    int p = tid / 3, c = tid - p * 3;
    vels[p][c] = cbuf[p][c] - c0s[p][c];
  }
  __syncthreads();
  if (tid < 3) {
    float s = 0.f;
    for (int p = 0; p < NP; ++p) s += vels[p][tid];
    velm[tid] = s / 22.0f;
  }
  __syncthreads();
  if (tid < NP * 3) {
    int p = tid / 3, c = tid - p * 3;
    out[b * (NP * 3) + tid] = vels[p][c] - velm[c];
  }
}

extern "C" void kernel_launch(void* const* d_in, const int* in_sizes, int n_in,
                              void* d_out, int out_size, void* d_ws, size_t ws_size,
                              hipStream_t stream) {
  const float* t    = (const float*)d_in[0];
  const float* x    = (const float*)d_in[1];
  const float* embW = (const float*)d_in[2];
  const float* embB = (const float*)d_in[3];
  // d_in[4] out_W, d_in[5] out_b: do not affect the returned velocities
  const float* ew1  = (const float*)d_in[6];
  const float* eb1  = (const float*)d_in[7];
  const float* ew2  = (const float*)d_in[8];
  const float* eb2  = (const float*)d_in[9];
  const float* nw1  = (const float*)d_in[10];
  const float* nb1  = (const float*)d_in[11];
  const float* nw2  = (const float*)d_in[12];
  const float* nb2  = (const float*)d_in[13];
  const float* cw1  = (const float*)d_in[14];
  const float* cb1  = (const float*)d_in[15];
  const float* cw2  = (const float*)d_in[16];
  const float* aw   = (const float*)d_in[17];
  const float* ab   = (const float*)d_in[18];
  // d_in[19] rows, d_in[20] cols: edge list regenerated analytically in-kernel

  egnn_kernel<<<1024, 256, 0, stream>>>(t, x, embW, embB, ew1, eb1, ew2, eb2,
                                        nw1, nb1, nw2, nb2, cw1, cb1, cw2,
                                        aw, ab, (float*)d_out);
}

// Round 4
// 1036.795 us; speedup vs baseline: 7.7970x; 2.2317x over previous
//
#include <hip/hip_runtime.h>

#define NP 22
#define NH 64
#define NL 5
#define NE 21

constexpr float CRc    = 3.0f;   // 15/L
constexpr float LOG2Mc = 7.0f;

typedef __fp16 h2_t  __attribute__((ext_vector_type(2)));
typedef __fp16 f16x8 __attribute__((ext_vector_type(8)));
typedef float  f32x16 __attribute__((ext_vector_type(16)));

__device__ __forceinline__ float rl_f(float v, int lane) {
  return __builtin_bit_cast(float, __builtin_amdgcn_readlane(__builtin_bit_cast(int, v), lane));
}
__device__ __forceinline__ h2_t rl_h2(h2_t v, int lane) {
  return __builtin_bit_cast(h2_t, __builtin_amdgcn_readlane(__builtin_bit_cast(int, v), lane));
}
__device__ __forceinline__ h2_t pkf(float a, float b) {
  return __builtin_amdgcn_cvt_pkrtz(a, b);
}
template <int CTRL>
__device__ __forceinline__ float dppmov(float v) {
  return __builtin_bit_cast(float,
      __builtin_amdgcn_update_dpp(0, __builtin_bit_cast(int, v), CTRL, 0xF, 0xF, true));
}
// lane 2i ends up holding (v[2i], v[2i+1]) — valid in even lanes.
__device__ __forceinline__ h2_t pkpair(float v) {
  float o = dppmov<0xB1>(v);          // swap within lane pairs
  return pkf(v, o);
}
// sum over each 32-lane group (bits 0-4)
__device__ __forceinline__ float red32(float v) {
  v += dppmov<0xB1>(v);               // xor 1 (quad_perm 1,0,3,2)
  v += dppmov<0x4E>(v);               // xor 2 (quad_perm 2,3,0,1)
  v += dppmov<0x124>(v);              // row_ror:4
  v += dppmov<0x128>(v);              // row_ror:8
  v += __builtin_bit_cast(float, __builtin_amdgcn_ds_swizzle(
         __builtin_bit_cast(int, v), 0x401F));   // xor 16
  return v;
}
__device__ __forceinline__ float fdot2(h2_t a, h2_t b, float c) {
#if __has_builtin(__builtin_amdgcn_fdot2)
  return __builtin_amdgcn_fdot2(a, b, c, false);
#else
  float d;
  asm("v_dot2_f32_f16 %0, %1, %2, %3"
      : "=v"(d)
      : "v"(__builtin_bit_cast(int, a)), "v"(__builtin_bit_cast(int, b)), "v"(c));
  return d;
#endif
}
__device__ __forceinline__ float siluf(float s) { return s / (1.0f + __expf(-s)); }

// y_j = INIT + sum_k src[k] * Wpk[k][j], src pair-packed per-lane (read even lanes)
#define GEMV_PK(OUT, SRC, W, INIT) do {                                     \
  float _a0 = (INIT), _a1 = 0.f, _a2 = 0.f, _a3 = 0.f;                      \
  _Pragma("unroll")                                                         \
  for (int _c = 0; _c < 32; _c += 4) {                                      \
    _a0 = fdot2(rl_h2((SRC), 2 * (_c + 0)), W[_c + 0], _a0);                \
    _a1 = fdot2(rl_h2((SRC), 2 * (_c + 1)), W[_c + 1], _a1);                \
    _a2 = fdot2(rl_h2((SRC), 2 * (_c + 2)), W[_c + 2], _a2);                \
    _a3 = fdot2(rl_h2((SRC), 2 * (_c + 3)), W[_c + 3], _a3);                \
  }                                                                         \
  OUT = (_a0 + _a1) + (_a2 + _a3);                                          \
} while (0)

#define LOADW(DST, SRC) do {                                                \
  _Pragma("unroll")                                                         \
  for (int _c = 0; _c < 32; ++_c)                                           \
    DST[_c] = pkf((SRC)[(2 * _c) * NH + lane],                              \
                  (SRC)[(2 * _c + 1) * NH + lane]);                         \
} while (0)

__global__ __launch_bounds__(256, 2) void egnn_kernel(
    const float* __restrict__ t,   const float* __restrict__ x,
    const float* __restrict__ embW, const float* __restrict__ embB,
    const float* __restrict__ ew1, const float* __restrict__ eb1,
    const float* __restrict__ ew2, const float* __restrict__ eb2,
    const float* __restrict__ nw1, const float* __restrict__ nb1,
    const float* __restrict__ nw2, const float* __restrict__ nb2,
    const float* __restrict__ cw1, const float* __restrict__ cb1,
    const float* __restrict__ cw2, const float* __restrict__ aw,
    const float* __restrict__ ab,  float* __restrict__ out)
{
  // edge-activation staging, f16-packed words, per wave: 32 edges x 32 words
  __shared__ int   amg[4][1024];          // 16 KB
  // B-fragments for W2 (s=0) and C1 (s=1): block=(s*4+ks)*2+n, 256 words each
  __shared__ int   wlds[4096];            // 16 KB
  __shared__ float h_lds[NP * 64];        // fp32 master h
  __shared__ float hibuf[NP * 64];        // hi_part / ubuf
  __shared__ float hcbuf[NP * 64];        // hc_part
  __shared__ float aggbuf[NP * 64];
  __shared__ float eas[NP * NE];
  __shared__ float edat[4][32][4];        // per-wave (dx,dy,dz,radial)
  __shared__ float cbuf[NP][4], c0s[NP][4], cupd[NP][4], vels[NP][4];
  __shared__ float velm[4];

  const int b = blockIdx.x, tid = threadIdx.x;
  const int lane = tid & 63, wv = tid >> 6;
  const int pl = (lane < NP) ? lane : 0;
  const int c31 = lane & 31;

  // ---- init
  if (tid < NP * 3) {
    int p = tid / 3, c = tid - p * 3;
    float v = x[b * (NP * 3) + tid];
    c0s[p][c] = v; cbuf[p][c] = v;
  }
  float tb = t[b];
  for (int p = wv; p < NP; p += 4)
    h_lds[p * 64 + lane] = embW[p * NH + lane] + tb * embW[22 * NH + lane]
                         + LOG2Mc * embW[23 * NH + lane] + embB[lane];
  __syncthreads();
  for (int idx = tid; idx < NP * NE; idx += 256) {
    int r = idx / NE, e = idx - r * NE, col = e + (e >= r);
    float dx = c0s[r][0] - c0s[col][0];
    float dy = c0s[r][1] - c0s[col][1];
    float dz = c0s[r][2] - c0s[col][2];
    eas[idx] = dx * dx + dy * dy + dz * dz;
  }
  __syncthreads();
  float cTx = cbuf[pl][0], cTy = cbuf[pl][1], cTz = cbuf[pl][2];

  for (int l = 0; l < NL; ++l) {
    const float* W1 = ew1 + l * 130 * NH;
    const float* W2 = ew2 + l * NH * NH;
    const float* C1 = cw1 + l * NH * NH;
    const float* N1 = nw1 + l * 128 * NH;
    const float* N2 = nw2 + l * NH * NH;

    float w128r = W1[128 * NH + lane], w129r = W1[129 * NH + lane];
    float b1r  = eb1[l * NH + lane];
    float b2r0 = eb2[l * NH + c31],  b2r1 = eb2[l * NH + 32 + c31];
    float awr0 = aw[l * NH + c31],   awr1 = aw[l * NH + 32 + c31];
    float abl  = ab[l];
    float cb1r0 = cb1[l * NH + c31], cb1r1 = cb1[l * NH + 32 + c31];
    float c2r0 = cw2[l * NH + c31],  c2r1 = cw2[l * NH + 32 + c31];

    // ---- B-fragment fill (W2, C1) — cooperative
    for (int blk = wv; blk < 16; blk += 4) {
      int s = blk >> 3, ks = (blk >> 1) & 3, n = blk & 1;
      const float* Wsrc = (s == 0) ? W2 : C1;
      int k0 = ks * 16 + (lane >> 5) * 8;
      int ch = n * 32 + c31;
      int base = blk * 256 + lane * 4;
#pragma unroll
      for (int w = 0; w < 4; ++w) {
        h2_t p = pkf(Wsrc[(k0 + 2 * w) * NH + ch], Wsrc[(k0 + 2 * w + 1) * NH + ch]);
        wlds[base + w] = __builtin_bit_cast(int, p);
      }
    }

    // ---- phase 0: hi_part / hc_part per atom
    {
      h2_t wA[32], wB[32];
      LOADW(wA, W1);                // W1 rows 0..63  (h[row] half)
      LOADW(wB, W1 + 64 * NH);      // W1 rows 64..127 (h[col] half)
      for (int r = wv; r < NP; r += 4) {
        float hv = h_lds[r * 64 + lane];
        h2_t hp = pkpair(hv);
        float hi; GEMV_PK(hi, hp, wA, b1r);
        hibuf[r * 64 + lane] = hi;
        float hc; GEMV_PK(hc, hp, wB, 0.0f);
        hcbuf[r * 64 + lane] = hc;
      }
    }
    __syncthreads();

    // ---- phase 1+2: per-row edge pipeline
    const int arow = c31 * 32;
    const int axor = (lane & 7) << 2;
    const int kh   = (lane >> 5) * 4;
    for (int r = wv; r < NP; r += 4) {
      float hii = hibuf[r * 64 + lane];
      float cix = rl_f(cTx, r), ciy = rl_f(cTy, r), ciz = rl_f(cTz, r);

      // phase 1: m1 for 21 edges (lane = channel), staged as f16 A-rows
      for (int e = 0; e < NE; ++e) {
        int col = e + (e >= r);
        float ccx = rl_f(cTx, col), ccy = rl_f(cTy, col), ccz = rl_f(cTz, col);
        float dx = cix - ccx, dy = ciy - ccy, dz = ciz - ccz;
        float radial = dx * dx + dy * dy + dz * dz;
        if (lane < 4) {
          float ev = (lane == 0) ? dx : (lane == 1) ? dy : (lane == 2) ? dz : radial;
          edat[wv][e][lane] = ev;
        }
        float s1 = hii + hcbuf[col * 64 + lane];
        s1 = fmaf(radial, w128r, s1);
        s1 = fmaf(eas[r * NE + e], w129r, s1);
        float m1 = siluf(s1);
        h2_t p = pkpair(m1);
        if (!(lane & 1))
          amg[wv][e * 32 + (((lane & 63) >> 1) ^ ((e & 7) << 2))] = __builtin_bit_cast(int, p);
      }

      // MFMA stage 1: m1 @ W2
      f32x16 acc0, acc1;
#pragma unroll
      for (int i = 0; i < 16; ++i) { acc0[i] = 0.f; acc1[i] = 0.f; }
#pragma unroll
      for (int ks = 0; ks < 4; ++ks) {
        int woff = (ks * 8 + kh) ^ axor;
        f16x8 af = __builtin_bit_cast(f16x8, *(const int4*)&amg[wv][arow + woff]);
        f16x8 b0 = __builtin_bit_cast(f16x8, *(const int4*)&wlds[(ks * 2 + 0) * 256 + lane * 4]);
        f16x8 b1 = __builtin_bit_cast(f16x8, *(const int4*)&wlds[(ks * 2 + 1) * 256 + lane * 4]);
        acc0 = __builtin_amdgcn_mfma_f32_32x32x16_f16(af, b0, acc0, 0, 0, 0);
        acc1 = __builtin_amdgcn_mfma_f32_32x32x16_f16(af, b1, acc1, 0, 0, 0);
      }

      // post1: silu, attention gate, agg, restage mg
      float aggn0 = 0.f, aggn1 = 0.f;
#pragma unroll
      for (int q = 0; q < 16; ++q) {
        int e = (q & 3) + 8 * (q >> 2) + 4 * (lane >> 5);
        float m20 = siluf(acc0[q] + b2r0);
        float m21 = siluf(acc1[q] + b2r1);
        float g = red32(m20 * awr0 + m21 * awr1) + abl;
        float sg = 1.0f / (1.0f + __expf(-g));
        float mg0 = m20 * sg, mg1 = m21 * sg;
        bool valid = (e < NE);
        aggn0 += valid ? mg0 : 0.f;
        aggn1 += valid ? mg1 : 0.f;
        float o0 = dppmov<0xB1>(mg0), o1 = dppmov<0xB1>(mg1);
        if (!(lane & 1)) {
          int ex = (e & 7) << 2;
          amg[wv][e * 32 + (((c31 >> 1)     ) ^ ex)] = __builtin_bit_cast(int, pkf(mg0, o0));
          amg[wv][e * 32 + ((16 + (c31 >> 1)) ^ ex)] = __builtin_bit_cast(int, pkf(mg1, o1));
        }
      }
      aggn0 += __shfl_xor(aggn0, 32, 64);
      aggn1 += __shfl_xor(aggn1, 32, 64);
      if (lane < 32) {
        aggbuf[r * 64 + lane]      = aggn0;
        aggbuf[r * 64 + 32 + lane] = aggn1;
      }

      // MFMA stage 2: mg @ C1
#pragma unroll
      for (int i = 0; i < 16; ++i) { acc0[i] = 0.f; acc1[i] = 0.f; }
#pragma unroll
      for (int ks = 0; ks < 4; ++ks) {
        int woff = (ks * 8 + kh) ^ axor;
        f16x8 af = __builtin_bit_cast(f16x8, *(const int4*)&amg[wv][arow + woff]);
        f16x8 b0 = __builtin_bit_cast(f16x8, *(const int4*)&wlds[(8 + ks * 2 + 0) * 256 + lane * 4]);
        f16x8 b1 = __builtin_bit_cast(f16x8, *(const int4*)&wlds[(8 + ks * 2 + 1) * 256 + lane * 4]);
        acc0 = __builtin_amdgcn_mfma_f32_32x32x16_f16(af, b0, acc0, 0, 0, 0);
        acc1 = __builtin_amdgcn_mfma_f32_32x32x16_f16(af, b1, acc1, 0, 0, 0);
      }

      // post2: coord MLP epilogue
      float cax = 0.f, cay = 0.f, caz = 0.f;
#pragma unroll
      for (int q = 0; q < 16; ++q) {
        int e = (q & 3) + 8 * (q >> 2) + 4 * (lane >> 5);
        float c10 = siluf(acc0[q] + cb1r0);
        float c11 = siluf(acc1[q] + cb1r1);
        float d = red32(c10 * c2r0 + c11 * c2r1);
        float ex2 = __expf(2.0f * d);
        float th = 1.0f - 2.0f / (1.0f + ex2);
        float tv = (e < NE) ? th * CRc : 0.f;
        float4 ed = *(const float4*)&edat[wv][e][0];
        float f = tv / (sqrtf(fmaxf(ed.w, 0.f)) + 1.0f);
        cax = fmaf(ed.x, f, cax);
        cay = fmaf(ed.y, f, cay);
        caz = fmaf(ed.z, f, caz);
      }
      cax += __shfl_xor(cax, 32, 64);
      cay += __shfl_xor(cay, 32, 64);
      caz += __shfl_xor(caz, 32, 64);
      if (lane < 3) {
        float cv = (lane == 0) ? cax : (lane == 1) ? cay : caz;
        cupd[r][lane] = cv;
      }
    }

    // ---- phase 3: node update (two passes to cap live weight regs)
    {
      h2_t wA[32], wB[32];
      LOADW(wA, N1);                // h half
      LOADW(wB, N1 + 64 * NH);      // agg half
      float nb1r = nb1[l * NH + lane];
      for (int r = wv; r < NP; r += 4) {
        float hv = h_lds[r * 64 + lane];
        h2_t hp = pkpair(hv);
        float s1; GEMV_PK(s1, hp, wA, nb1r);
        float ag = aggbuf[r * 64 + lane];
        h2_t agp = pkpair(ag);
        float s2; GEMV_PK(s2, agp, wB, s1);
        hibuf[r * 64 + lane] = s2;  // ubuf (reuse)
      }
    }
    {
      h2_t wC[32];
      LOADW(wC, N2);
      float nb2r = nb2[l * NH + lane];
      for (int r = wv; r < NP; r += 4) {
        float u = hibuf[r * 64 + lane];
        float v = siluf(u);
        h2_t vp = pkpair(v);
        float q; GEMV_PK(q, vp, wC, nb2r);
        h_lds[r * 64 + lane] += q;
      }
    }
    __syncthreads();
    if (tid < NP * 3) {
      int p = tid / 3, c = tid - p * 3;
      cbuf[p][c] += cupd[p][c];
    }
    __syncthreads();
    cTx = cbuf[pl][0]; cTy = cbuf[pl][1]; cTz = cbuf[pl][2];
  }

  // ---- output: vel = coord - coord0, mean-removed
  if (tid < NP * 3) {
    int p = tid / 3, c = tid - p * 3;
    vels[p][c] = cbuf[p][c] - c0s[p][c];
  }
  __syncthreads();
  if (tid < 3) {
    float s = 0.f;
    for (int p = 0; p < NP; ++p) s += vels[p][tid];
    velm[tid] = s / 22.0f;
  }
  __syncthreads();
  if (tid < NP * 3) {
    int p = tid / 3, c = tid - p * 3;
    out[b * (NP * 3) + tid] = vels[p][c] - velm[c];
  }
}

extern "C" void kernel_launch(void* const* d_in, const int* in_sizes, int n_in,
                              void* d_out, int out_size, void* d_ws, size_t ws_size,
                              hipStream_t stream) {
  const float* t    = (const float*)d_in[0];
  const float* x    = (const float*)d_in[1];
  const float* embW = (const float*)d_in[2];
  const float* embB = (const float*)d_in[3];
  // d_in[4] out_W, d_in[5] out_b: do not affect the returned velocities
  const float* ew1  = (const float*)d_in[6];
  const float* eb1  = (const float*)d_in[7];
  const float* ew2  = (const float*)d_in[8];
  const float* eb2  = (const float*)d_in[9];
  const float* nw1  = (const float*)d_in[10];
  const float* nb1  = (const float*)d_in[11];
  const float* nw2  = (const float*)d_in[12];
  const float* nb2  = (const float*)d_in[13];
  const float* cw1  = (const float*)d_in[14];
  const float* cb1  = (const float*)d_in[15];
  const float* cw2  = (const float*)d_in[16];
  const float* aw   = (const float*)d_in[17];
  const float* ab   = (const float*)d_in[18];
  // d_in[19] rows, d_in[20] cols: edge list regenerated analytically in-kernel

  egnn_kernel<<<1024, 256, 0, stream>>>(t, x, embW, embB, ew1, eb1, ew2, eb2,
                                        nw1, nb1, nw2, nb2, cw1, cb1, cw2,
                                        aw, ab, (float*)d_out);
}

// Round 5
// 728.551 us; speedup vs baseline: 11.0959x; 1.4231x over previous
//
#include <hip/hip_runtime.h>

#define NP 22
#define NH 64
#define NL 5
#define NE 21

constexpr float CRc    = 3.0f;   // 15/L
constexpr float LOG2Mc = 7.0f;
constexpr float L2E    = 1.442695041f;

typedef __fp16 h2_t  __attribute__((ext_vector_type(2)));
typedef __fp16 f16x8 __attribute__((ext_vector_type(8)));
typedef float  f32x16 __attribute__((ext_vector_type(16)));

// ---- native single-instruction transcendentals (harness has no -ffast-math;
//      libm paths expand to 8-19 instr IEEE sequences — the R4 bottleneck)
__device__ __forceinline__ float rcp_(float x) {
#if __has_builtin(__builtin_amdgcn_rcpf)
  return __builtin_amdgcn_rcpf(x);
#else
  float r; asm("v_rcp_f32 %0, %1" : "=v"(r) : "v"(x)); return r;
#endif
}
__device__ __forceinline__ float exp2_(float x) {
#if __has_builtin(__builtin_amdgcn_exp2f)
  return __builtin_amdgcn_exp2f(x);
#else
  float r; asm("v_exp_f32 %0, %1" : "=v"(r) : "v"(x)); return r;
#endif
}
__device__ __forceinline__ float sqrt_(float x) {
#if __has_builtin(__builtin_amdgcn_sqrtf)
  return __builtin_amdgcn_sqrtf(x);
#else
  float r; asm("v_sqrt_f32 %0, %1" : "=v"(r) : "v"(x)); return r;
#endif
}
__device__ __forceinline__ float sigf(float s)  { return rcp_(1.0f + exp2_(-L2E * s)); }
__device__ __forceinline__ float siluf(float s) { return s * sigf(s); }

__device__ __forceinline__ float rl_f(float v, int lane) {
  return __builtin_bit_cast(float, __builtin_amdgcn_readlane(__builtin_bit_cast(int, v), lane));
}
__device__ __forceinline__ h2_t pkf(float a, float b) {
  return __builtin_amdgcn_cvt_pkrtz(a, b);
}
template <int CTRL>
__device__ __forceinline__ float dppmov(float v) {
  return __builtin_bit_cast(float,
      __builtin_amdgcn_update_dpp(0, __builtin_bit_cast(int, v), CTRL, 0xF, 0xF, true));
}
// lane 2i holds (v[2i], v[2i+1]) — valid in even lanes.
__device__ __forceinline__ h2_t pkpair(float v) {
  float o = dppmov<0xB1>(v);
  return pkf(v, o);
}
// sum over each 32-lane group
__device__ __forceinline__ float red32(float v) {
  v += dppmov<0xB1>(v);
  v += dppmov<0x4E>(v);
  v += dppmov<0x124>(v);
  v += dppmov<0x128>(v);
  v += __builtin_bit_cast(float, __builtin_amdgcn_ds_swizzle(
         __builtin_bit_cast(int, v), 0x401F));
  return v;
}

__global__ __launch_bounds__(256, 2) void egnn_kernel(
    const float* __restrict__ t,   const float* __restrict__ x,
    const float* __restrict__ embW, const float* __restrict__ embB,
    const float* __restrict__ ew1, const float* __restrict__ eb1,
    const float* __restrict__ ew2, const float* __restrict__ eb2,
    const float* __restrict__ nw1, const float* __restrict__ nb1,
    const float* __restrict__ nw2, const float* __restrict__ nb2,
    const float* __restrict__ cw1, const float* __restrict__ cb1,
    const float* __restrict__ cw2, const float* __restrict__ aw,
    const float* __restrict__ ab,  float* __restrict__ out)
{
  __shared__ __align__(16) int   wlds[4096];      // B-fragments (16KB, reused 4x/layer)
  __shared__ __align__(16) int   amg[4][1024];    // per-wave edge A-tiles
  __shared__ __align__(16) int   h16w[1024];      // h as swizzled f16 A-tile [32][32w]
  __shared__ __align__(16) float h_lds[NP * 64];  // fp32 master h
  __shared__ __align__(16) float hibuf[NP * 64];  // hi_part; reused as ubuf
  __shared__ __align__(16) int   hc_agg[NP * 64]; // hcbuf (f32) then agg16 tile
  __shared__ __align__(16) int   agg_u[NP * 64];  // aggbuf (f32) then u16 tile
  __shared__ __align__(16) float eas[NP * NE];
  __shared__ __align__(16) float edat[4][32][4];
  __shared__ float cbuf[NP][4], c0s[NP][4], cupd[NP][4], vels[NP][4];
  __shared__ float velm[4];

  float* hcbuf  = (float*)hc_agg;
  int*   agg16w = hc_agg;
  float* aggbuf = (float*)agg_u;
  int*   u16w   = agg_u;

  const int b = blockIdx.x, tid = threadIdx.x;
  const int lane = tid & 63, wv = tid >> 6;
  const int pl = (lane < NP) ? lane : 0;
  const int c31 = lane & 31;
  const int hh = lane >> 5;
  const int xorv = ((lane >> 3) & 7) << 2;   // wlds B-read swizzle

  // ---- B-fragment fill: blocks [0,nblocks); blk<8 from Wlo rows kb*16.., else Whi
  auto fillblk = [&](const float* Wlo, const float* Whi, int nblocks) {
    for (int blk = wv; blk < nblocks; blk += 4) {
      const float* Ws = (blk < 8) ? Wlo : Whi;
      int kb = (blk >> 1) & 3, n = blk & 1;
      int k0 = kb * 16 + hh * 8;
      int ch = n * 32 + c31;
      int wb = blk * 256 + ((lane * 4) ^ xorv);
#pragma unroll
      for (int w = 0; w < 4; ++w) {
        h2_t p = pkf(Ws[(k0 + 2 * w) * NH + ch], Ws[(k0 + 2 * w + 1) * NH + ch]);
        wlds[wb + w] = __builtin_bit_cast(int, p);
      }
    }
  };
  auto bread = [&](int blk) -> f16x8 {
    return __builtin_bit_cast(f16x8, *(const int4*)&wlds[blk * 256 + ((lane * 4) ^ xorv)]);
  };
  // A-read from swizzled [32 rows][32 words] f16 tile
  auto aread = [&](const int* tile, int ks) -> f16x8 {
    int off = (ks * 8 + hh * 4) ^ ((c31 & 7) << 2);
    return __builtin_bit_cast(f16x8, *(const int4*)&tile[c31 * 32 + off]);
  };
  // pack fp32 [NP][64] -> swizzled f16 tile (rows >= NP zeroed)
  auto packtile = [&](int* dst, const float* src, bool dosilu) {
    for (int idx = tid; idx < 1024; idx += 256) {
      int atom = idx >> 5, w = idx & 31;
      int v = 0;
      if (atom < NP) {
        float a = src[atom * 64 + 2 * w], bq = src[atom * 64 + 2 * w + 1];
        if (dosilu) { a = siluf(a); bq = siluf(bq); }
        v = __builtin_bit_cast(int, pkf(a, bq));
      }
      dst[atom * 32 + (w ^ ((atom & 7) << 2))] = v;
    }
  };

  // ---- init
  if (tid < NP * 3) {
    int p = tid / 3, c = tid - p * 3;
    float v = x[b * (NP * 3) + tid];
    c0s[p][c] = v; cbuf[p][c] = v;
  }
  for (int idx = tid; idx < 512; idx += 256) ((float*)edat)[idx] = 0.f;  // NaN guard
  float tb = t[b];
  for (int p = wv; p < NP; p += 4)
    h_lds[p * 64 + lane] = embW[p * NH + lane] + tb * embW[22 * NH + lane]
                         + LOG2Mc * embW[23 * NH + lane] + embB[lane];
  __syncthreads();
  for (int idx = tid; idx < NP * NE; idx += 256) {
    int r = idx / NE, e = idx - r * NE, col = e + (e >= r);
    float dx = c0s[r][0] - c0s[col][0];
    float dy = c0s[r][1] - c0s[col][1];
    float dz = c0s[r][2] - c0s[col][2];
    eas[idx] = dx * dx + dy * dy + dz * dz;
  }
  packtile(h16w, h_lds, false);
  float cTx = cbuf[pl][0], cTy = cbuf[pl][1], cTz = cbuf[pl][2];
  __syncthreads();

  for (int l = 0; l < NL; ++l) {
    const float* W1 = ew1 + l * 130 * NH;
    const float* W2 = ew2 + l * NH * NH;
    const float* C1 = cw1 + l * NH * NH;
    const float* N1 = nw1 + l * 128 * NH;
    const float* N2 = nw2 + l * NH * NH;

    // step1: wlds <- W1 rows 0..127
    fillblk(W1, W1 + 64 * NH, 16);
    __syncthreads();

    // step2: phase0 — hi = h@W1[0:64]+b1 (waves 0,1), hc = h@W1[64:128] (waves 2,3)
    {
      int s = wv >> 1, n = wv & 1;
      f32x16 acc;
#pragma unroll
      for (int i = 0; i < 16; ++i) acc[i] = 0.f;
#pragma unroll
      for (int ks = 0; ks < 4; ++ks)
        acc = __builtin_amdgcn_mfma_f32_32x32x16_f16(aread(h16w, ks),
                bread((s * 4 + ks) * 2 + n), acc, 0, 0, 0);
      int ch = n * 32 + c31;
      float bias = (s == 0) ? eb1[l * NH + ch] : 0.0f;
      float* dst = (s == 0) ? hibuf : hcbuf;
#pragma unroll
      for (int q = 0; q < 16; ++q) {
        int atom = (q & 3) + 8 * (q >> 2) + 4 * hh;
        if (atom < NP) dst[atom * 64 + ch] = acc[q] + bias;
      }
    }
    __syncthreads();

    // step3: wlds <- W2 (blocks 0-7), C1 (blocks 8-15)
    fillblk(W2, C1, 16);
    __syncthreads();

    // step4: edge phase (per-row)
    float w128r = W1[128 * NH + lane], w129r = W1[129 * NH + lane];
    float b2r0 = eb2[l * NH + c31],  b2r1 = eb2[l * NH + 32 + c31];
    float awr0 = aw[l * NH + c31],   awr1 = aw[l * NH + 32 + c31];
    float abl  = ab[l];
    float cb1r0 = cb1[l * NH + c31], cb1r1 = cb1[l * NH + 32 + c31];
    float c2r0 = cw2[l * NH + c31],  c2r1 = cw2[l * NH + 32 + c31];

    const int arow = c31 * 32;
    const int axor = (c31 & 7) << 2;
    const int kh   = hh * 4;
    for (int r = wv; r < NP; r += 4) {
      float hii = hibuf[r * 64 + lane];
      float cix = rl_f(cTx, r), ciy = rl_f(cTy, r), ciz = rl_f(cTz, r);

      // phase 1: m1 for 21 edges (lane = channel)
      for (int e = 0; e < NE; ++e) {
        int col = e + (e >= r);
        float ccx = rl_f(cTx, col), ccy = rl_f(cTy, col), ccz = rl_f(cTz, col);
        float dx = cix - ccx, dy = ciy - ccy, dz = ciz - ccz;
        float radial = dx * dx + dy * dy + dz * dz;
        if (lane < 4) {
          float ev = (lane == 0) ? dx : (lane == 1) ? dy : (lane == 2) ? dz : radial;
          edat[wv][e][lane] = ev;
        }
        float s1 = hii + hcbuf[col * 64 + lane];
        s1 = fmaf(radial, w128r, s1);
        s1 = fmaf(eas[r * NE + e], w129r, s1);
        float m1 = siluf(s1);
        h2_t p = pkpair(m1);
        if (!(lane & 1))
          amg[wv][e * 32 + ((lane >> 1) ^ ((e & 7) << 2))] = __builtin_bit_cast(int, p);
      }

      // MFMA stage 1: m1 @ W2
      f32x16 acc0, acc1;
#pragma unroll
      for (int i = 0; i < 16; ++i) { acc0[i] = 0.f; acc1[i] = 0.f; }
#pragma unroll
      for (int ks = 0; ks < 4; ++ks) {
        int woff = (ks * 8 + kh) ^ axor;
        f16x8 af = __builtin_bit_cast(f16x8, *(const int4*)&amg[wv][arow + woff]);
        acc0 = __builtin_amdgcn_mfma_f32_32x32x16_f16(af, bread(ks * 2 + 0), acc0, 0, 0, 0);
        acc1 = __builtin_amdgcn_mfma_f32_32x32x16_f16(af, bread(ks * 2 + 1), acc1, 0, 0, 0);
      }

      // post1: silu, attention gate, agg, restage mg
      float aggn0 = 0.f, aggn1 = 0.f;
#pragma unroll
      for (int q = 0; q < 16; ++q) {
        int e = (q & 3) + 8 * (q >> 2) + 4 * hh;
        float m20 = siluf(acc0[q] + b2r0);
        float m21 = siluf(acc1[q] + b2r1);
        float g = red32(m20 * awr0 + m21 * awr1) + abl;
        float sg = sigf(g);
        float mg0 = m20 * sg, mg1 = m21 * sg;
        bool valid = (e < NE);
        aggn0 += valid ? mg0 : 0.f;
        aggn1 += valid ? mg1 : 0.f;
        float o0 = dppmov<0xB1>(mg0), o1 = dppmov<0xB1>(mg1);
        if (!(lane & 1)) {
          int ex = (e & 7) << 2;
          amg[wv][e * 32 + (((c31 >> 1)     ) ^ ex)] = __builtin_bit_cast(int, pkf(mg0, o0));
          amg[wv][e * 32 + ((16 + (c31 >> 1)) ^ ex)] = __builtin_bit_cast(int, pkf(mg1, o1));
        }
      }
      aggn0 += __shfl_xor(aggn0, 32, 64);
      aggn1 += __shfl_xor(aggn1, 32, 64);
      if (lane < 32) {
        aggbuf[r * 64 + lane]      = aggn0;
        aggbuf[r * 64 + 32 + lane] = aggn1;
      }

      // MFMA stage 2: mg @ C1
#pragma unroll
      for (int i = 0; i < 16; ++i) { acc0[i] = 0.f; acc1[i] = 0.f; }
#pragma unroll
      for (int ks = 0; ks < 4; ++ks) {
        int woff = (ks * 8 + kh) ^ axor;
        f16x8 af = __builtin_bit_cast(f16x8, *(const int4*)&amg[wv][arow + woff]);
        acc0 = __builtin_amdgcn_mfma_f32_32x32x16_f16(af, bread(8 + ks * 2 + 0), acc0, 0, 0, 0);
        acc1 = __builtin_amdgcn_mfma_f32_32x32x16_f16(af, bread(8 + ks * 2 + 1), acc1, 0, 0, 0);
      }

      // post2: coord MLP epilogue
      float cax = 0.f, cay = 0.f, caz = 0.f;
#pragma unroll
      for (int q = 0; q < 16; ++q) {
        int e = (q & 3) + 8 * (q >> 2) + 4 * hh;
        float c10 = siluf(acc0[q] + cb1r0);
        float c11 = siluf(acc1[q] + cb1r1);
        float d = red32(c10 * c2r0 + c11 * c2r1);
        float th = 1.0f - 2.0f * rcp_(1.0f + exp2_(2.0f * L2E * d));   // tanh(d)
        float tv = (e < NE) ? th * CRc : 0.f;
        float4 ed = *(const float4*)&edat[wv][e][0];
        float f = tv * rcp_(sqrt_(fmaxf(ed.w, 0.f)) + 1.0f);
        cax = fmaf(ed.x, f, cax);
        cay = fmaf(ed.y, f, cay);
        caz = fmaf(ed.z, f, caz);
      }
      cax += __shfl_xor(cax, 32, 64);
      cay += __shfl_xor(cay, 32, 64);
      caz += __shfl_xor(caz, 32, 64);
      if (lane < 3) {
        float cv = (lane == 0) ? cax : (lane == 1) ? cay : caz;
        cupd[r][lane] = cv;
      }
    }
    __syncthreads();

    // step5: wlds <- N1 rows 0..127; pack agg A-tile
    fillblk(N1, N1 + 64 * NH, 16);
    packtile(agg16w, aggbuf, false);
    __syncthreads();

    // step6: node stage1 — u = h@N1[0:64] + agg@N1[64:128] + nb1 (waves 0,1)
    if (wv < 2) {
      int n = wv;
      f32x16 acc;
#pragma unroll
      for (int i = 0; i < 16; ++i) acc[i] = 0.f;
#pragma unroll
      for (int ks = 0; ks < 4; ++ks)
        acc = __builtin_amdgcn_mfma_f32_32x32x16_f16(aread(h16w, ks),
                bread(ks * 2 + n), acc, 0, 0, 0);
#pragma unroll
      for (int ks = 0; ks < 4; ++ks)
        acc = __builtin_amdgcn_mfma_f32_32x32x16_f16(aread(agg16w, ks),
                bread((4 + ks) * 2 + n), acc, 0, 0, 0);
      int ch = n * 32 + c31;
      float bias = nb1[l * NH + ch];
#pragma unroll
      for (int q = 0; q < 16; ++q) {
        int atom = (q & 3) + 8 * (q >> 2) + 4 * hh;
        if (atom < NP) hibuf[atom * 64 + ch] = acc[q] + bias;   // ubuf
      }
    }
    __syncthreads();

    // step7: u16 <- silu(ubuf); wlds blocks 0-7 <- N2
    fillblk(N2, N2, 8);
    packtile(u16w, hibuf, true);
    __syncthreads();

    // step8: node stage2 — h += silu(u)@N2 + nb2 (waves 0,1); coords (others)
    if (wv < 2) {
      int n = wv;
      f32x16 acc;
#pragma unroll
      for (int i = 0; i < 16; ++i) acc[i] = 0.f;
#pragma unroll
      for (int ks = 0; ks < 4; ++ks)
        acc = __builtin_amdgcn_mfma_f32_32x32x16_f16(aread(u16w, ks),
                bread(ks * 2 + n), acc, 0, 0, 0);
      int ch = n * 32 + c31;
      float bias = nb2[l * NH + ch];
#pragma unroll
      for (int q = 0; q < 16; ++q) {
        int atom = (q & 3) + 8 * (q >> 2) + 4 * hh;
        if (atom < NP) h_lds[atom * 64 + ch] += acc[q] + bias;
      }
    }
    {
      int ci = tid - 128;
      if (ci >= 0 && ci < NP * 3) {
        int p = ci / 3, c = ci - 3 * p;
        cbuf[p][c] += cupd[p][c];
      }
    }
    __syncthreads();

    // step9: repack h16; refresh coord registers
    packtile(h16w, h_lds, false);
    cTx = cbuf[pl][0]; cTy = cbuf[pl][1]; cTz = cbuf[pl][2];
    __syncthreads();
  }

  // ---- output: vel = coord - coord0, mean-removed
  if (tid < NP * 3) {
    int p = tid / 3, c = tid - p * 3;
    vels[p][c] = cbuf[p][c] - c0s[p][c];
  }
  __syncthreads();
  if (tid < 3) {
    float s = 0.f;
    for (int p = 0; p < NP; ++p) s += vels[p][tid];
    velm[tid] = s / 22.0f;
  }
  __syncthreads();
  if (tid < NP * 3) {
    int p = tid / 3, c = tid - p * 3;
    out[b * (NP * 3) + tid] = vels[p][c] - velm[c];
  }
}

extern "C" void kernel_launch(void* const* d_in, const int* in_sizes, int n_in,
                              void* d_out, int out_size, void* d_ws, size_t ws_size,
                              hipStream_t stream) {
  const float* t    = (const float*)d_in[0];
  const float* x    = (const float*)d_in[1];
  const float* embW = (const float*)d_in[2];
  const float* embB = (const float*)d_in[3];
  // d_in[4] out_W, d_in[5] out_b: do not affect the returned velocities
  const float* ew1  = (const float*)d_in[6];
  const float* eb1  = (const float*)d_in[7];
  const float* ew2  = (const float*)d_in[8];
  const float* eb2  = (const float*)d_in[9];
  const float* nw1  = (const float*)d_in[10];
  const float* nb1  = (const float*)d_in[11];
  const float* nw2  = (const float*)d_in[12];
  const float* nb2  = (const float*)d_in[13];
  const float* cw1  = (const float*)d_in[14];
  const float* cb1  = (const float*)d_in[15];
  const float* cw2  = (const float*)d_in[16];
  const float* aw   = (const float*)d_in[17];
  const float* ab   = (const float*)d_in[18];
  // d_in[19] rows, d_in[20] cols: edge list regenerated analytically in-kernel

  egnn_kernel<<<1024, 256, 0, stream>>>(t, x, embW, embB, ew1, eb1, ew2, eb2,
                                        nw1, nb1, nw2, nb2, cw1, cb1, cw2,
                                        aw, ab, (float*)d_out);
}